// Round 2
// baseline (1192.551 us; speedup 1.0000x reference)
//
#include <hip/hip_runtime.h>
#include <math.h>

#define Bq 64
#define Tq 1024
#define Nq 128
#define CHAINS 4   // chains per block

typedef __attribute__((ext_vector_type(2))) float f32x2;

// ---------------------------------------------------------------------------
// Forward algorithm. 4 chains per block (512 threads, 8 waves -> 2 waves/SIMD).
// Thread (c, n) owns state n of chain c. E-column exp(trans[:,n]) lives in 64
// f32x2 VGPR pairs (pinned). Per step: ONE barrier (double-buffered p),
// no max-reduce (running stabilizer M derived identically by all threads from
// p[0..3]), 128 MACs done as 64 v_pk_fma_f32 into 4 independent accumulators.
// ---------------------------------------------------------------------------
__global__ __launch_bounds__(512, 2)
void crf_forward_kernel(const float* __restrict__ emissions,
                        const int* __restrict__ token_sizes,
                        const float* __restrict__ transitions,
                        const float* __restrict__ head,
                        const float* __restrict__ last,
                        float* __restrict__ out) {
    const int tid = threadIdx.x;
    const int c = tid >> 7;          // chain within block, 0..3
    const int n = tid & 127;         // state index 0..127
    const int b = blockIdx.x * CHAINS + c;

    __shared__ __align__(16) float pbuf[CHAINS][2][Nq];
    __shared__ float redA[CHAINS][2];
    __shared__ float redB[CHAINS][2];

    // E column n in registers: e2[j] = (exp(T[2j][n]), exp(T[2j+1][n]))
    f32x2 e2[Nq / 2];
    #pragma unroll
    for (int j = 0; j < Nq / 2; ++j) {
        f32x2 v;
        v.x = __expf(transitions[(2 * j)     * Nq + n]);
        v.y = __expf(transitions[(2 * j + 1) * Nq + n]);
        e2[j] = v;
    }
    // Pin to VGPRs: opaque touch prevents rematerialization / scratch spill.
    #pragma unroll
    for (int j = 0; j < Nq / 2; ++j) asm volatile("" : "+v"(e2[j]));

    const float* em = emissions + (size_t)b * Tq * Nq;
    const int tsz = token_sizes[b];          // in [T/2, T]

    // block-uniform loop bound: max tsz over the block's chains
    const int b0 = blockIdx.x * CHAINS;
    int maxTsz = token_sizes[b0];
    maxTsz = max(maxTsz, token_sizes[b0 + 1]);
    maxTsz = max(maxTsz, token_sizes[b0 + 2]);
    maxTsz = max(maxTsz, token_sizes[b0 + 3]);

    float a = head[n] + em[n];               // alpha_0
    float M = 0.0f;                          // running stabilizer (uniform per chain)

    // depth-2 emission prefetch (tsz >= 512 so t=1,2 exist)
    float emitA = em[1 * Nq + n];
    float emitB = em[2 * Nq + n];

    int buf = 0;
    for (int t = 1; t < maxTsz; ++t) {
        float p = __expf(a - M);
        pbuf[c][buf][n] = p;
        __syncthreads();

        // prefetch emissions for t+2 (clamped, stays in-bounds)
        float emitC = em[min(t + 2, maxTsz - 1) * Nq + n];

        const float4* p4 = (const float4*)pbuf[c][buf];
        f32x2 accs[4];
        accs[0] = (f32x2)(0.f); accs[1] = (f32x2)(0.f);
        accs[2] = (f32x2)(0.f); accs[3] = (f32x2)(0.f);
        float pm = 0.0f;
        #pragma unroll
        for (int g = 0; g < Nq / 4; ++g) {
            float4 pv = p4[g];
            if (g == 0) pm = fmaxf(fmaxf(pv.x, pv.y), fmaxf(pv.z, pv.w));
            f32x2 plo; plo.x = pv.x; plo.y = pv.y;
            f32x2 phi; phi.x = pv.z; phi.y = pv.w;
            asm("v_pk_fma_f32 %0, %1, %2, %0"
                : "+v"(accs[(2 * g) & 3]) : "v"(plo), "v"(e2[2 * g]));
            asm("v_pk_fma_f32 %0, %1, %2, %0"
                : "+v"(accs[(2 * g + 1) & 3]) : "v"(phi), "v"(e2[2 * g + 1]));
        }
        f32x2 sv = (accs[0] + accs[1]) + (accs[2] + accs[3]);
        float s = sv.x + sv.y;

        float na = M + __logf(s) + emitA;
        if (t < tsz) a = na;                  // freeze past this chain's length
        M += __logf(pm);                      // uniform: same p[0..3], same ops
        emitA = emitB;
        emitB = emitC;
        buf ^= 1;
    }

    // log_partitions[b] = lse_n(alpha[n] + last[n])
    float v = a + last[n];
    float w = v;
    #pragma unroll
    for (int off = 32; off >= 1; off >>= 1)
        w = fmaxf(w, __shfl_xor(w, off, 64));
    if ((n & 63) == 0) redA[c][n >> 6] = w;
    __syncthreads();
    float mx = fmaxf(redA[c][0], redA[c][1]);
    float pe = __expf(v - mx);
    float sum = pe;
    #pragma unroll
    for (int off = 32; off >= 1; off >>= 1)
        sum += __shfl_xor(sum, off, 64);
    if ((n & 63) == 0) redB[c][n >> 6] = sum;
    __syncthreads();
    if (n == 0) out[b] = mx + __logf(redB[c][0] + redB[c][1]);
}

// ---------------------------------------------------------------------------
// Gold-path score — masked gather-sum per batch.
// ---------------------------------------------------------------------------
__global__ __launch_bounds__(256)
void crf_score_kernel(const float* __restrict__ emissions,
                      const int* __restrict__ token_sizes,
                      const int* __restrict__ targets,
                      const float* __restrict__ transitions,
                      const float* __restrict__ head,
                      const float* __restrict__ last,
                      float* __restrict__ out) {
    const int b = blockIdx.x;
    const int tid = threadIdx.x;
    const int tsz = token_sizes[b];
    const int* tg = targets + b * Tq;
    const float* em = emissions + (size_t)b * Tq * Nq;

    float local = 0.f;
    for (int t = tid; t < tsz; t += 256) {
        int cur = tg[t];
        local += em[t * Nq + cur];
        if (t >= 1) local += transitions[tg[t - 1] * Nq + cur];
    }
    #pragma unroll
    for (int off = 32; off >= 1; off >>= 1)
        local += __shfl_xor(local, off, 64);

    __shared__ float wsum[4];
    if ((tid & 63) == 0) wsum[tid >> 6] = local;
    __syncthreads();
    if (tid == 0) {
        float tot = wsum[0] + wsum[1] + wsum[2] + wsum[3];
        tot += head[tg[0]] + last[tg[tsz - 1]];
        out[Bq + b] = tot;
    }
}

extern "C" void kernel_launch(void* const* d_in, const int* in_sizes, int n_in,
                              void* d_out, int out_size, void* d_ws, size_t ws_size,
                              hipStream_t stream) {
    const float* emissions   = (const float*)d_in[0];
    const int*   token_sizes = (const int*)d_in[1];
    const int*   targets     = (const int*)d_in[2];
    const float* transitions = (const float*)d_in[3];  // (1,1,128,128)
    const float* head        = (const float*)d_in[4];  // (1,1,128)
    const float* last        = (const float*)d_in[5];  // (1,1,128)
    float* out = (float*)d_out;                        // (2,64,1) flat

    crf_forward_kernel<<<Bq / CHAINS, 512, 0, stream>>>(emissions, token_sizes,
                                                        transitions, head, last, out);
    crf_score_kernel<<<Bq, 256, 0, stream>>>(emissions, token_sizes, targets,
                                             transitions, head, last, out);
}

// Round 3
// 560.277 us; speedup vs baseline: 2.1285x; 2.1285x over previous
//
#include <hip/hip_runtime.h>
#include <math.h>

#define Bq 64
#define Tq 1024
#define Nq 128

typedef __attribute__((ext_vector_type(2))) _Float16 h2;

#if defined(__has_builtin)
#  if __has_builtin(__builtin_amdgcn_fdot2)
#    define HAVE_FDOT2 1
#  endif
#endif

__device__ __forceinline__ float dot2acc(h2 a, h2 b, float c) {
#ifdef HAVE_FDOT2
    return __builtin_amdgcn_fdot2(a, b, c, false);
#else
    return c + (float)a.x * (float)b.x + (float)a.y * (float)b.y;
#endif
}

// ---------------------------------------------------------------------------
// Fused CRF kernel: one wave (64 threads) per batch chain. Lane L owns states
// L and L+64. E columns (exp(trans)) live in 128 f16x2 VGPRs (asm-pinned,
// cap 512 via launch_bounds(64,1) so spill/remat never pays). Per step:
//   p = exp(alpha - M) -> f16 -> LDS (256 B),  1-wave syncthreads,
//   16 broadcast ds_read_b128, 128 v_dot2_f32_f16 into 4+4 accumulators,
//   alpha = M + log(s) + emit,  M = max4(alpha_prev) + 7 (uniform, no reduce).
// No barriers across waves, per-chain early exit at own tsz.
// Tail: wave-reduce lse -> out[b]; gold-path score -> out[64+b].
// ---------------------------------------------------------------------------
__global__ __launch_bounds__(64, 1)
void crf_fused_kernel(const float* __restrict__ emissions,
                      const int* __restrict__ token_sizes,
                      const int* __restrict__ targets,
                      const float* __restrict__ transitions,
                      const float* __restrict__ head,
                      const float* __restrict__ last,
                      float* __restrict__ out) {
    const int b = blockIdx.x;
    const int L = threadIdx.x;        // lane 0..63
    const int n0 = L;
    const int n1 = L + 64;

    __shared__ __align__(16) _Float16 p_lds[Nq];

    // ---- E columns for states n0, n1 as f16 pairs over m (pair j = m 2j,2j+1)
    h2 eA[Nq / 2], eB[Nq / 2];
    #pragma unroll
    for (int j = 0; j < Nq / 2; ++j) {
        h2 va, vb;
        va.x = (_Float16)__expf(transitions[(2 * j)     * Nq + n0]);
        va.y = (_Float16)__expf(transitions[(2 * j + 1) * Nq + n0]);
        vb.x = (_Float16)__expf(transitions[(2 * j)     * Nq + n1]);
        vb.y = (_Float16)__expf(transitions[(2 * j + 1) * Nq + n1]);
        eA[j] = va;
        eB[j] = vb;
    }
    // Opaque redefinition: values are no longer rematerializable from memory.
    #pragma unroll
    for (int j = 0; j < Nq / 2; ++j) asm volatile("" : "+v"(eA[j]), "+v"(eB[j]));

    const float* em = emissions + (size_t)b * Tq * Nq;
    const int tsz = token_sizes[b];   // in [T/2, T]

    float aA = head[n0] + em[n0];
    float aB = head[n1] + em[n1];

    // uniform stabilizer init: true max of alpha0 (one-time wave reduce)
    float M;
    {
        float w = fmaxf(aA, aB);
        #pragma unroll
        for (int off = 32; off >= 1; off >>= 1)
            w = fmaxf(w, __shfl_xor(w, off, 64));
        M = w;
    }

    // depth-2 emission prefetch (tsz >= 512 so t=1,2 exist)
    float fA0 = em[1 * Nq + n0], fB0 = em[1 * Nq + n1];
    float fA1 = em[2 * Nq + n0], fB1 = em[2 * Nq + n1];

    for (int t = 1; t < tsz; ++t) {
        float pA = fminf(__expf(aA - M), 60000.0f);
        float pB = fminf(__expf(aB - M), 60000.0f);
        p_lds[n0] = (_Float16)pA;
        p_lds[n1] = (_Float16)pB;

        // prefetch emissions for t+2 (clamped in-bounds)
        const int tn = min(t + 2, tsz - 1);
        float fA2 = em[tn * Nq + n0], fB2 = em[tn * Nq + n1];

        __syncthreads();   // single-wave block: ~free, orders LDS ops

        const h2* pp = (const h2*)p_lds;   // 64 pairs, broadcast reads
        float sA[4] = {0.f, 0.f, 0.f, 0.f};
        float sB[4] = {0.f, 0.f, 0.f, 0.f};
        float pm = 0.0f;
        #pragma unroll
        for (int j = 0; j < Nq / 2; ++j) {
            h2 pj = pp[j];
            if (j == 0) pm = fmaxf((float)pj.x, (float)pj.y);
            if (j == 1) pm = fmaxf(pm, fmaxf((float)pj.x, (float)pj.y));
            sA[j & 3] = dot2acc(pj, eA[j], sA[j & 3]);
            sB[j & 3] = dot2acc(pj, eB[j], sB[j & 3]);
        }
        float ssA = (sA[0] + sA[1]) + (sA[2] + sA[3]);
        float ssB = (sB[0] + sB[1]) + (sB[2] + sB[3]);

        aA = M + __logf(ssA) + fA0;
        aB = M + __logf(ssB) + fB0;
        // next stabilizer: max4(alpha(t-1)) + 7  (uniform across lanes)
        pm = fmaxf(pm, 1e-6f);
        M += __logf(pm) + 7.0f;

        fA0 = fA1; fB0 = fB1;
        fA1 = fA2; fB1 = fB2;
    }

    // ---- log_partitions[b] = lse over 128 states (2 per lane) ----
    {
        float vA = aA + last[n0];
        float vB = aB + last[n1];
        float w = fmaxf(vA, vB);
        #pragma unroll
        for (int off = 32; off >= 1; off >>= 1)
            w = fmaxf(w, __shfl_xor(w, off, 64));
        float sum = __expf(vA - w) + __expf(vB - w);
        #pragma unroll
        for (int off = 32; off >= 1; off >>= 1)
            sum += __shfl_xor(sum, off, 64);
        if (L == 0) out[b] = w + __logf(sum);
    }

    // ---- gold-path score -> out[64+b] (lane-strided gather-sum) ----
    {
        const int* tg = targets + b * Tq;
        float sc = 0.f;
        for (int t = L; t < tsz; t += 64) {
            int cur = tg[t];
            sc += em[t * Nq + cur];
            if (t >= 1) sc += transitions[tg[t - 1] * Nq + cur];
        }
        #pragma unroll
        for (int off = 32; off >= 1; off >>= 1)
            sc += __shfl_xor(sc, off, 64);
        if (L == 0) out[Bq + b] = sc + head[tg[0]] + last[tg[tsz - 1]];
    }
}

extern "C" void kernel_launch(void* const* d_in, const int* in_sizes, int n_in,
                              void* d_out, int out_size, void* d_ws, size_t ws_size,
                              hipStream_t stream) {
    const float* emissions   = (const float*)d_in[0];
    const int*   token_sizes = (const int*)d_in[1];
    const int*   targets     = (const int*)d_in[2];
    const float* transitions = (const float*)d_in[3];  // (1,1,128,128)
    const float* head        = (const float*)d_in[4];  // (1,1,128)
    const float* last        = (const float*)d_in[5];  // (1,1,128)
    float* out = (float*)d_out;                        // (2,64,1) flat

    crf_fused_kernel<<<Bq, 64, 0, stream>>>(emissions, token_sizes, targets,
                                            transitions, head, last, out);
}